// Round 5
// baseline (381.986 us; speedup 1.0000x reference)
//
#include <hip/hip_runtime.h>

#define EPS   0.01f
#define ALPHA 0.1f
#define H     60

typedef __attribute__((ext_vector_type(8))) short short8;
typedef __attribute__((ext_vector_type(4))) float float4v;

__device__ __forceinline__ float softplusf(float x) {
    float e = __expf(-fabsf(x));
    return fmaxf(x, 0.f) + __logf(1.f + e);
}
__device__ __forceinline__ unsigned bf16_rne(float x) {
    unsigned u = __builtin_bit_cast(unsigned, x);
    return (u + 0x7FFFu + ((u >> 16) & 1u)) >> 16;   // round-nearest-even
}
__device__ __forceinline__ float bf16f(unsigned h) {
    return __builtin_bit_cast(float, h << 16);
}
// MFMA 16x16x32 A/B per-lane k map: element j -> k = 8*(lane>>4) + j  (contiguous).
// If wrong (absmax garbage), flip to: (j<4) ? 4*q+j : 16+4*q+(j-4).
__device__ __forceinline__ int kmap(int q, int j) { return q * 8 + j; }

// ws float layout: [0]=g0 | [16..272) kt float4[64] | [272..528) nt float4[64]
//                  | [528..2576) B1hi u32[2048] | [2576..4624) B1lo | [4624..6672) B2
#define WS_KT  16
#define WS_NT  272
#define WS_B1  528

__global__ void setup_kernel(const float* __restrict__ W1, const float* __restrict__ b1,
                             const float* __restrict__ W2, const float* __restrict__ b2,
                             const float* __restrict__ W3, const float* __restrict__ b3,
                             const float* __restrict__ Wim2, float* __restrict__ ws) {
    const int tid = threadIdx.x;
    float4*   kt  = (float4*)(ws + WS_KT);
    float4*   nt4 = (float4*)(ws + WS_NT);
    unsigned* B1hi = (unsigned*)(ws + WS_B1);
    unsigned* B1lo = B1hi + 2048;
    unsigned* B2t  = B1lo + 2048;

    if (tid < 64) {
        float4 kv = make_float4(0.f, 0.f, 0.f, 0.f);
        float4 nv = make_float4(0.f, 0.f, 0.f, 0.f);
        if (tid < H) {
            kv.x = W1[2 * tid]; kv.y = W1[2 * tid + 1]; kv.z = b1[tid];
            nv.x = b2[tid]; nv.y = Wim2[2 * tid]; nv.z = Wim2[2 * tid + 1]; nv.w = W3[tid];
        }
        kt[tid] = kv; nt4[tid] = nv;
    }
    for (int idx = tid; idx < 2048; idx += 256) {
        const int frag = idx >> 2, rp = idx & 3;
        const int l = frag & 63, t2 = frag >> 6;
        const int kh = t2 & 1, nt = t2 >> 1;
        const int n  = nt * 16 + (l & 15);
        const int ka = kh * 32 + kmap(l >> 4, rp * 2);
        const int kb = kh * 32 + kmap(l >> 4, rp * 2 + 1);
        // GEMM1: B[k][n] = W2^T[k][n] = W2[n][k]
        float v0 = (ka < H && n < H) ? W2[n * H + ka] : 0.f;
        float v1 = (kb < H && n < H) ? W2[n * H + kb] : 0.f;
        unsigned h0 = bf16_rne(v0), h1 = bf16_rne(v1);
        B1hi[idx] = h0 | (h1 << 16);
        unsigned l0 = bf16_rne(v0 - bf16f(h0)), l1 = bf16_rne(v1 - bf16f(h1));
        B1lo[idx] = l0 | (l1 << 16);
        // GEMM2: B[k][n] = W2[k][n]   (k = j index, n = k2 index)
        float w0 = (ka < H && n < H) ? W2[ka * H + n] : 0.f;
        float w1 = (kb < H && n < H) ? W2[kb * H + n] : 0.f;
        B2t[idx] = bf16_rne(w0) | (bf16_rne(w1) << 16);
    }
    if (tid == 0) {
        float h1v[H];
        for (int k = 0; k < H; ++k) h1v[k] = softplusf(b1[k]);
        float z3 = b3[0];
        for (int j = 0; j < H; ++j) {
            float acc = b2[j];
            for (int k = 0; k < H; ++k) acc = fmaf(W2[j * H + k], h1v[k], acc);
            z3 = fmaf(W3[j], softplusf(acc), z3);
        }
        ws[0] = softplusf(z3);
    }
}

__global__ __launch_bounds__(256) void fused_kernel(
    const float* __restrict__ X, const float* __restrict__ Wf,
    const float* __restrict__ Wim3, const float* __restrict__ b3,
    const float* __restrict__ ws, float* __restrict__ out, int B)
{
    __shared__ unsigned sB1hi[2048], sB1lo[2048], sB2[2048];  // 24 KB
    __shared__ float4 sKT[64], sNT[64];                       // 2 KB
    __shared__ float2 sX[256];                                // 2 KB
    __shared__ unsigned short sT[4][1024];                    // 8 KB, per-wave 16x64 bf16 swizzled

    const int tid = threadIdx.x;
    const unsigned* gB1 = (const unsigned*)(ws + WS_B1);
    for (int i = tid; i < 2048; i += 256) {
        sB1hi[i] = gB1[i];
        sB1lo[i] = gB1[2048 + i];
        sB2[i]   = gB1[4096 + i];
    }
    if (tid < 64) {
        sKT[tid] = ((const float4*)(ws + WS_KT))[tid];
        sNT[tid] = ((const float4*)(ws + WS_NT))[tid];
    }
    const int rows0 = blockIdx.x * 256;
    {
        int r = rows0 + tid;
        sX[tid] = (r < B) ? ((const float2*)X)[r] : make_float2(0.f, 0.f);
    }
    __syncthreads();

    const float g0  = ws[0];
    const float b3v = b3[0], wi30 = Wim3[0], wi31 = Wim3[1];
    const float wf0 = Wf[0], wf1 = Wf[1], wf2 = Wf[2], wf3 = Wf[3];

    const int wid = tid >> 6, lane = tid & 63;
    const int m = lane & 15, qd = lane >> 4;

    for (int blk = 0; blk < 4; ++blk) {
        const int rloc = wid * 64 + blk * 16;

        // ---- layer 1 -> A-fragments (hi/lo bf16) ----
        const float2 xa = sX[rloc + m];
        short8 Ahi[2], Alo[2];
#pragma unroll
        for (int kh = 0; kh < 2; ++kh) {
#pragma unroll
            for (int j = 0; j < 8; ++j) {
                const int k = kh * 32 + kmap(qd, j);
                const float4 kv = sKT[k];
                const float z1 = fmaf(kv.x, xa.x, fmaf(kv.y, xa.y, kv.z));
                const float h1 = softplusf(z1);
                const unsigned hi = bf16_rne(h1);
                const unsigned lo = bf16_rne(h1 - bf16f(hi));
                Ahi[kh][j] = (short)hi;
                Alo[kh][j] = (short)lo;
            }
        }

        // ---- GEMM1: z2 = h1 * W2^T  (split-precision, 3 passes) ----
        float4v acc[4];
#pragma unroll
        for (int nt = 0; nt < 4; ++nt) acc[nt] = (float4v){0.f, 0.f, 0.f, 0.f};
#pragma unroll
        for (int nt = 0; nt < 4; ++nt) {
#pragma unroll
            for (int kh = 0; kh < 2; ++kh) {
                const int fi = ((nt * 2 + kh) * 64 + lane) * 4;
                const short8 bhi = *(const short8*)&sB1hi[fi];
                const short8 blo = *(const short8*)&sB1lo[fi];
                acc[nt] = __builtin_amdgcn_mfma_f32_16x16x32_bf16(Ahi[kh], bhi, acc[nt], 0, 0, 0);
                acc[nt] = __builtin_amdgcn_mfma_f32_16x16x32_bf16(Alo[kh], bhi, acc[nt], 0, 0, 0);
                acc[nt] = __builtin_amdgcn_mfma_f32_16x16x32_bf16(Ahi[kh], blo, acc[nt], 0, 0, 0);
            }
        }

        // ---- epilogue 1: z2 -> h2, t; z3/gim partials; t -> swizzled LDS tile ----
        float xr0[4], xr1[4];
#pragma unroll
        for (int c = 0; c < 4; ++c) {
            const float2 xx = sX[rloc + qd * 4 + c];
            xr0[c] = xx.x; xr1[c] = xx.y;
        }
        float zp[4]  = {0.f, 0.f, 0.f, 0.f};
        float gi0[4] = {0.f, 0.f, 0.f, 0.f};
        float gi1[4] = {0.f, 0.f, 0.f, 0.f};
#pragma unroll
        for (int nt = 0; nt < 4; ++nt) {
            const float4 nv = sNT[nt * 16 + m];   // {b2, wim2_0, wim2_1, w3} (0 for pad)
#pragma unroll
            for (int c = 0; c < 4; ++c) {
                const float z2 = acc[nt][c] + fmaf(nv.y, xr0[c], fmaf(nv.z, xr1[c], nv.x));
                const float h2 = softplusf(z2);
                zp[c] = fmaf(nv.w, h2, zp[c]);
                const float tj = nv.w * (1.f - __expf(-h2));   // w3 * sigmoid(z2)
                gi0[c] = fmaf(tj, nv.y, gi0[c]);
                gi1[c] = fmaf(tj, nv.z, gi1[c]);
                const int row = qd * 4 + c;
                const int byteoff = (row * 128 + (nt * 16 + m) * 2) ^ ((row & 7) << 4);
                sT[wid][byteoff >> 1] = (unsigned short)bf16_rne(tj);
            }
        }
#pragma unroll
        for (int c = 0; c < 4; ++c) {
#pragma unroll
            for (int msk = 1; msk < 16; msk <<= 1) {
                zp[c]  += __shfl_xor(zp[c],  msk);
                gi0[c] += __shfl_xor(gi0[c], msk);
                gi1[c] += __shfl_xor(gi1[c], msk);
            }
        }

        // ---- GEMM2: G = t * W2 ----
        short8 TA[2];
#pragma unroll
        for (int kh = 0; kh < 2; ++kh) {
            const int byteoff = (m * 128 + kh * 64 + qd * 16) ^ ((m & 7) << 4);
            TA[kh] = *(const short8*)((const char*)&sT[wid][0] + byteoff);
        }
        float4v gacc[4];
#pragma unroll
        for (int nt = 0; nt < 4; ++nt) gacc[nt] = (float4v){0.f, 0.f, 0.f, 0.f};
#pragma unroll
        for (int nt = 0; nt < 4; ++nt) {
#pragma unroll
            for (int kh = 0; kh < 2; ++kh) {
                const short8 bb = *(const short8*)&sB2[((nt * 2 + kh) * 64 + lane) * 4];
                gacc[nt] = __builtin_amdgcn_mfma_f32_16x16x32_bf16(TA[kh], bb, gacc[nt], 0, 0, 0);
            }
        }

        // ---- epilogue 2: u1 = G * sigmoid(z1); q partials ----
        float qp0[4] = {0.f, 0.f, 0.f, 0.f}, qp1[4] = {0.f, 0.f, 0.f, 0.f};
#pragma unroll
        for (int nt = 0; nt < 4; ++nt) {
            const float4 kv = sKT[nt * 16 + m];   // {w1k0, w1k1, b1k} for k = nt*16+m
#pragma unroll
            for (int c = 0; c < 4; ++c) {
                const float z1 = fmaf(kv.x, xr0[c], fmaf(kv.y, xr1[c], kv.z));
                const float sg = __fdividef(1.f, 1.f + __expf(-z1));
                const float u1 = gacc[nt][c] * sg;
                qp0[c] = fmaf(u1, kv.x, qp0[c]);
                qp1[c] = fmaf(u1, kv.y, qp1[c]);
            }
        }
#pragma unroll
        for (int c = 0; c < 4; ++c) {
#pragma unroll
            for (int msk = 1; msk < 16; msk <<= 1) {
                qp0[c] += __shfl_xor(qp0[c], msk);
                qp1[c] += __shfl_xor(qp1[c], msk);
            }
        }

        // ---- final per-row scalar math + store ----
#pragma unroll
        for (int c = 0; c < 4; ++c) {
            const float x0 = xr0[c], x1 = xr1[c];
            const float z3 = zp[c] + fmaf(wi30, x0, fmaf(wi31, x1, b3v));
            const float g  = softplusf(z3);
            const float u3 = (g > g0) ? (1.f - __expf(-g)) : 0.f;
            const float dv0 = fmaf(2.f * EPS, x0, u3 * (wi30 + gi0[c] + qp0[c]));
            const float dv1 = fmaf(2.f * EPS, x1, u3 * (wi31 + gi1[c] + qp1[c]));
            const float V  = fmaxf(g - g0, 0.f) + EPS * fmaf(x0, x0, x1 * x1);
            const float f0 = fmaf(wf0, x0, wf1 * x1);
            const float f1 = fmaf(wf2, x0, wf3 * x1);
            const float stab = fmaf(ALPHA, V, fmaf(dv0, f0, dv1 * f1));
            const float s = __fdividef(fmaxf(stab, 0.f), fmaf(dv0, dv0, dv1 * dv1));
            if (m == c) {
                const int grow = rows0 + rloc + qd * 4 + c;
                if (grow < B) ((float2*)out)[grow] = make_float2(f0 - dv0 * s, f1 - dv1 * s);
            }
        }
    }
}

// ---- fallback (round-2 monolithic) if ws is too small ----
__global__ void g0_kernel(const float* __restrict__ W2, const float* __restrict__ b1,
                          const float* __restrict__ b2, const float* __restrict__ W3,
                          const float* __restrict__ b3, float* __restrict__ g0_out) {
    if (threadIdx.x != 0 || blockIdx.x != 0) return;
    float h1[H];
    for (int k = 0; k < H; ++k) h1[k] = softplusf(b1[k]);
    float z3 = b3[0];
    for (int j = 0; j < H; ++j) {
        float acc = b2[j];
        for (int k = 0; k < H; ++k) acc = fmaf(W2[j * H + k], h1[k], acc);
        z3 = fmaf(W3[j], softplusf(acc), z3);
    }
    g0_out[0] = softplusf(z3);
}

__global__ __launch_bounds__(256) void sdnn_mono_kernel(
    const float* __restrict__ X,   const float* __restrict__ Wf,
    const float* __restrict__ W1,  const float* __restrict__ b1,
    const float* __restrict__ W2,  const float* __restrict__ b2,
    const float* __restrict__ W3,  const float* __restrict__ b3,
    const float* __restrict__ Wim2,const float* __restrict__ Wim3,
    const float* __restrict__ g0p, float* __restrict__ out, int B)
{
    const int row = blockIdx.x * 256 + threadIdx.x;
    if (row >= B) return;
    const float2 xv = ((const float2*)X)[row];
    const float x0 = xv.x, x1 = xv.y;
    float h1v[H];
#pragma unroll
    for (int k = 0; k < H; ++k)
        h1v[k] = softplusf(fmaf(W1[2 * k], x0, fmaf(W1[2 * k + 1], x1, b1[k])));
    float G[H];
#pragma unroll
    for (int k = 0; k < H; ++k) G[k] = 0.f;
    const float wi30 = Wim3[0], wi31 = Wim3[1];
    float z3 = fmaf(wi30, x0, fmaf(wi31, x1, b3[0]));
    float gim0 = 0.f, gim1 = 0.f;
    for (int j = 0; j < H; ++j) {
        const float* __restrict__ wrow = &W2[j * H];
        float a0 = 0.f, a1 = 0.f, a2 = 0.f, a3 = 0.f;
#pragma unroll
        for (int k = 0; k < H; k += 4) {
            a0 = fmaf(wrow[k + 0], h1v[k + 0], a0);
            a1 = fmaf(wrow[k + 1], h1v[k + 1], a1);
            a2 = fmaf(wrow[k + 2], h1v[k + 2], a2);
            a3 = fmaf(wrow[k + 3], h1v[k + 3], a3);
        }
        float acc = ((a0 + a1) + (a2 + a3))
                  + fmaf(Wim2[2 * j], x0, fmaf(Wim2[2 * j + 1], x1, b2[j]));
        const float h2  = softplusf(acc);
        const float w3j = W3[j];
        z3 = fmaf(w3j, h2, z3);
        const float tj = w3j * (1.f - __expf(-h2));
        gim0 = fmaf(tj, Wim2[2 * j],     gim0);
        gim1 = fmaf(tj, Wim2[2 * j + 1], gim1);
#pragma unroll
        for (int k = 0; k < H; ++k) G[k] = fmaf(wrow[k], tj, G[k]);
    }
    const float g0 = g0p[0];
    const float g  = softplusf(z3);
    const float u3 = (g > g0) ? (1.f - __expf(-g)) : 0.f;
    float q0 = 0.f, q1 = 0.f;
#pragma unroll
    for (int k = 0; k < H; ++k) {
        const float u1 = G[k] * (1.f - __expf(-h1v[k]));
        q0 = fmaf(u1, W1[2 * k],     q0);
        q1 = fmaf(u1, W1[2 * k + 1], q1);
    }
    const float dV0 = fmaf(2.f * EPS, x0, u3 * (wi30 + gim0 + q0));
    const float dV1 = fmaf(2.f * EPS, x1, u3 * (wi31 + gim1 + q1));
    const float V  = fmaxf(g - g0, 0.f) + EPS * fmaf(x0, x0, x1 * x1);
    const float f0 = fmaf(Wf[0], x0, Wf[1] * x1);
    const float f1 = fmaf(Wf[2], x0, Wf[3] * x1);
    const float stab = fmaf(ALPHA, V, fmaf(dV0, f0, dV1 * f1));
    const float s    = __fdividef(fmaxf(stab, 0.f), fmaf(dV0, dV0, dV1 * dV1));
    float2 o;
    o.x = f0 - dV0 * s;
    o.y = f1 - dV1 * s;
    ((float2*)out)[row] = o;
}

extern "C" void kernel_launch(void* const* d_in, const int* in_sizes, int n_in,
                              void* d_out, int out_size, void* d_ws, size_t ws_size,
                              hipStream_t stream) {
    const float* X    = (const float*)d_in[0];
    const float* Wf   = (const float*)d_in[1];
    const float* W1   = (const float*)d_in[2];
    const float* b1   = (const float*)d_in[3];
    const float* W2   = (const float*)d_in[4];
    const float* b2   = (const float*)d_in[5];
    const float* W3   = (const float*)d_in[6];
    const float* b3   = (const float*)d_in[7];
    const float* Wim2 = (const float*)d_in[8];
    const float* Wim3 = (const float*)d_in[9];
    float* out = (float*)d_out;
    float* wsf = (float*)d_ws;

    const int B = in_sizes[0] / 2;
    const int nwg = (B + 255) / 256;

    if (ws_size >= 6672u * 4u) {
        hipLaunchKernelGGL(setup_kernel, dim3(1), dim3(256), 0, stream,
                           W1, b1, W2, b2, W3, b3, Wim2, wsf);
        hipLaunchKernelGGL(fused_kernel, dim3(nwg), dim3(256), 0, stream,
                           X, Wf, Wim3, b3, wsf, out, B);
    } else {
        hipLaunchKernelGGL(g0_kernel, dim3(1), dim3(64), 0, stream,
                           W2, b1, b2, W3, b3, wsf);
        hipLaunchKernelGGL(sdnn_mono_kernel, dim3(nwg), dim3(256), 0, stream,
                           X, Wf, W1, b1, W2, b2, W3, b3, Wim2, Wim3, wsf, out, B);
    }
}

// Round 7
// 252.218 us; speedup vs baseline: 1.5145x; 1.5145x over previous
//
#include <hip/hip_runtime.h>

#define EPS   0.01f
#define ALPHA 0.1f
#define H     60

typedef _Float16 h2v __attribute__((ext_vector_type(2)));
typedef __fp16   fp16x2 __attribute__((ext_vector_type(2)));

__device__ __forceinline__ float softplusf(float x) {
    // stable: max(x,0) + log1p(exp(-|x|))
    float e = __expf(-fabsf(x));
    return fmaxf(x, 0.f) + __logf(1.f + e);
}

__device__ __forceinline__ h2v pk2h(float a, float b) {
    fp16x2 r = __builtin_amdgcn_cvt_pkrtz(a, b);   // v_cvt_pkrtz_f16_f32
    return __builtin_bit_cast(h2v, r);
}

// ws layout: [0]=g0 | ws+16: W2pk h2v[60*30]  (f16-packed W2 rows, pair over k)
#define WS_PK 16

// ---- setup: g0 scalar + f16-packed W2 rows ----
__global__ void setup_kernel(const float* __restrict__ W2, const float* __restrict__ b1,
                             const float* __restrict__ b2, const float* __restrict__ W3,
                             const float* __restrict__ b3, float* __restrict__ ws) {
    const int tid = threadIdx.x;
    h2v* W2pk = (h2v*)(ws + WS_PK);
    for (int idx = tid; idx < H * (H / 2); idx += 256) {
        const int j = idx / (H / 2), p = idx % (H / 2);
        W2pk[idx] = pk2h(W2[j * H + 2 * p], W2[j * H + 2 * p + 1]);
    }
    if (tid == 0) {
        float h1[H];
        for (int k = 0; k < H; ++k) h1[k] = softplusf(b1[k]);
        float z3 = b3[0];
        for (int j = 0; j < H; ++j) {
            float acc = b2[j];
            for (int k = 0; k < H; ++k) acc = fmaf(W2[j * H + k], h1[k], acc);
            z3 = fmaf(W3[j], softplusf(acc), z3);
        }
        ws[0] = softplusf(z3);
    }
}

// ---- main: one row per thread. Forward f32 (scalar W2 via s_load);
// backward G accumulated in packed f16 (v_pk_fma_f16) -> ~105 live VGPRs, no AGPR. ----
__global__ __launch_bounds__(256, 4) void sdnn_kernel(
    const float* __restrict__ X,   const float* __restrict__ Wf,
    const float* __restrict__ W1,  const float* __restrict__ b1,
    const float* __restrict__ W2,  const float* __restrict__ b2,
    const float* __restrict__ W3,  const float* __restrict__ b3,
    const float* __restrict__ Wim2,const float* __restrict__ Wim3,
    const float* __restrict__ ws,  float* __restrict__ out, int B)
{
    const int row = blockIdx.x * 256 + threadIdx.x;
    if (row >= B) return;

    const h2v* __restrict__ W2pk = (const h2v*)(ws + WS_PK);

    const float2 xv = ((const float2*)X)[row];
    const float x0 = xv.x, x1 = xv.y;

    // layer 1: h1 = sp(W1 x + b1)
    float h1v[H];
#pragma unroll
    for (int k = 0; k < H; ++k)
        h1v[k] = softplusf(fmaf(W1[2 * k], x0, fmaf(W1[2 * k + 1], x1, b1[k])));

    // G packed f16 pairs over k
    h2v Gpk[H / 2];
#pragma unroll
    for (int p = 0; p < H / 2; ++p) { Gpk[p][0] = (_Float16)0.f; Gpk[p][1] = (_Float16)0.f; }

    const float wi30 = Wim3[0], wi31 = Wim3[1];
    float z3 = fmaf(wi30, x0, fmaf(wi31, x1, b3[0]));
    float gim0 = 0.f, gim1 = 0.f;

    for (int j = 0; j < H; ++j) {
        const float* __restrict__ wrow = &W2[j * H];
        float a0 = 0.f, a1 = 0.f, a2 = 0.f, a3 = 0.f;
#pragma unroll
        for (int k = 0; k < H; k += 4) {
            a0 = fmaf(wrow[k + 0], h1v[k + 0], a0);
            a1 = fmaf(wrow[k + 1], h1v[k + 1], a1);
            a2 = fmaf(wrow[k + 2], h1v[k + 2], a2);
            a3 = fmaf(wrow[k + 3], h1v[k + 3], a3);
        }
        const float z2 = ((a0 + a1) + (a2 + a3))
                       + fmaf(Wim2[2 * j], x0, fmaf(Wim2[2 * j + 1], x1, b2[j]));
        const float e2 = __expf(-fabsf(z2));
        const float h2 = fmaxf(z2, 0.f) + __logf(1.f + e2);
        const float w3j = W3[j];
        z3 = fmaf(w3j, h2, z3);
        const float tj = w3j * (1.f - __expf(-h2));   // W3[j]*sigmoid(z2_j)
        gim0 = fmaf(tj, Wim2[2 * j],     gim0);
        gim1 = fmaf(tj, Wim2[2 * j + 1], gim1);

        const h2v t2 = pk2h(tj, tj);
        const h2v* __restrict__ wpk = W2pk + j * (H / 2);
#pragma unroll
        for (int p = 0; p < H / 2; ++p) Gpk[p] += wpk[p] * t2;   // v_pk_fma_f16
    }

    // backward finish: u1_k = G_k * sigmoid(z1_k) (sigmoid from h1: 1-exp(-h1))
    float q0 = 0.f, q1 = 0.f;
#pragma unroll
    for (int p = 0; p < H / 2; ++p) {
        const float Ga = (float)Gpk[p][0];
        const float Gb = (float)Gpk[p][1];
        const float ua = Ga * (1.f - __expf(-h1v[2 * p]));
        const float ub = Gb * (1.f - __expf(-h1v[2 * p + 1]));
        q0 = fmaf(ua, W1[4 * p],     fmaf(ub, W1[4 * p + 2], q0));
        q1 = fmaf(ua, W1[4 * p + 1], fmaf(ub, W1[4 * p + 3], q1));
    }

    const float g0 = ws[0];
    const float g  = softplusf(z3);
    const float u3 = (g > g0) ? (1.f - __expf(-g)) : 0.f;

    const float dV0 = fmaf(2.f * EPS, x0, u3 * (wi30 + gim0 + q0));
    const float dV1 = fmaf(2.f * EPS, x1, u3 * (wi31 + gim1 + q1));

    const float V  = fmaxf(g - g0, 0.f) + EPS * fmaf(x0, x0, x1 * x1);
    const float f0 = fmaf(Wf[0], x0, Wf[1] * x1);
    const float f1 = fmaf(Wf[2], x0, Wf[3] * x1);
    const float stab = fmaf(ALPHA, V, fmaf(dV0, f0, dV1 * f1));
    const float s    = __fdividef(fmaxf(stab, 0.f), fmaf(dV0, dV0, dV1 * dV1));

    float2 o;
    o.x = f0 - dV0 * s;
    o.y = f1 - dV1 * s;
    ((float2*)out)[row] = o;
}

// ---- fallback (round-2 monolithic) if ws is too small ----
__global__ void g0_kernel(const float* __restrict__ W2, const float* __restrict__ b1,
                          const float* __restrict__ b2, const float* __restrict__ W3,
                          const float* __restrict__ b3, float* __restrict__ g0_out) {
    if (threadIdx.x != 0 || blockIdx.x != 0) return;
    float h1[H];
    for (int k = 0; k < H; ++k) h1[k] = softplusf(b1[k]);
    float z3 = b3[0];
    for (int j = 0; j < H; ++j) {
        float acc = b2[j];
        for (int k = 0; k < H; ++k) acc = fmaf(W2[j * H + k], h1[k], acc);
        z3 = fmaf(W3[j], softplusf(acc), z3);
    }
    g0_out[0] = softplusf(z3);
}

__global__ __launch_bounds__(256) void sdnn_mono_kernel(
    const float* __restrict__ X,   const float* __restrict__ Wf,
    const float* __restrict__ W1,  const float* __restrict__ b1,
    const float* __restrict__ W2,  const float* __restrict__ b2,
    const float* __restrict__ W3,  const float* __restrict__ b3,
    const float* __restrict__ Wim2,const float* __restrict__ Wim3,
    const float* __restrict__ g0p, float* __restrict__ out, int B)
{
    const int row = blockIdx.x * 256 + threadIdx.x;
    if (row >= B) return;
    const float2 xv = ((const float2*)X)[row];
    const float x0 = xv.x, x1 = xv.y;
    float h1v[H];
#pragma unroll
    for (int k = 0; k < H; ++k)
        h1v[k] = softplusf(fmaf(W1[2 * k], x0, fmaf(W1[2 * k + 1], x1, b1[k])));
    float G[H];
#pragma unroll
    for (int k = 0; k < H; ++k) G[k] = 0.f;
    const float wi30 = Wim3[0], wi31 = Wim3[1];
    float z3 = fmaf(wi30, x0, fmaf(wi31, x1, b3[0]));
    float gim0 = 0.f, gim1 = 0.f;
    for (int j = 0; j < H; ++j) {
        const float* __restrict__ wrow = &W2[j * H];
        float a0 = 0.f, a1 = 0.f, a2 = 0.f, a3 = 0.f;
#pragma unroll
        for (int k = 0; k < H; k += 4) {
            a0 = fmaf(wrow[k + 0], h1v[k + 0], a0);
            a1 = fmaf(wrow[k + 1], h1v[k + 1], a1);
            a2 = fmaf(wrow[k + 2], h1v[k + 2], a2);
            a3 = fmaf(wrow[k + 3], h1v[k + 3], a3);
        }
        float acc = ((a0 + a1) + (a2 + a3))
                  + fmaf(Wim2[2 * j], x0, fmaf(Wim2[2 * j + 1], x1, b2[j]));
        const float h2  = softplusf(acc);
        const float w3j = W3[j];
        z3 = fmaf(w3j, h2, z3);
        const float tj = w3j * (1.f - __expf(-h2));
        gim0 = fmaf(tj, Wim2[2 * j],     gim0);
        gim1 = fmaf(tj, Wim2[2 * j + 1], gim1);
#pragma unroll
        for (int k = 0; k < H; ++k) G[k] = fmaf(wrow[k], tj, G[k]);
    }
    const float g0 = g0p[0];
    const float g  = softplusf(z3);
    const float u3 = (g > g0) ? (1.f - __expf(-g)) : 0.f;
    float q0 = 0.f, q1 = 0.f;
#pragma unroll
    for (int k = 0; k < H; ++k) {
        const float u1 = G[k] * (1.f - __expf(-h1v[k]));
        q0 = fmaf(u1, W1[2 * k],     q0);
        q1 = fmaf(u1, W1[2 * k + 1], q1);
    }
    const float dV0 = fmaf(2.f * EPS, x0, u3 * (wi30 + gim0 + q0));
    const float dV1 = fmaf(2.f * EPS, x1, u3 * (wi31 + gim1 + q1));
    const float V  = fmaxf(g - g0, 0.f) + EPS * fmaf(x0, x0, x1 * x1);
    const float f0 = fmaf(Wf[0], x0, Wf[1] * x1);
    const float f1 = fmaf(Wf[2], x0, Wf[3] * x1);
    const float stab = fmaf(ALPHA, V, fmaf(dV0, f0, dV1 * f1));
    const float s    = __fdividef(fmaxf(stab, 0.f), fmaf(dV0, dV0, dV1 * dV1));
    float2 o;
    o.x = f0 - dV0 * s;
    o.y = f1 - dV1 * s;
    ((float2*)out)[row] = o;
}

extern "C" void kernel_launch(void* const* d_in, const int* in_sizes, int n_in,
                              void* d_out, int out_size, void* d_ws, size_t ws_size,
                              hipStream_t stream) {
    const float* X    = (const float*)d_in[0];
    const float* Wf   = (const float*)d_in[1];
    const float* W1   = (const float*)d_in[2];
    const float* b1   = (const float*)d_in[3];
    const float* W2   = (const float*)d_in[4];
    const float* b2   = (const float*)d_in[5];
    const float* W3   = (const float*)d_in[6];
    const float* b3   = (const float*)d_in[7];
    const float* Wim2 = (const float*)d_in[8];
    const float* Wim3 = (const float*)d_in[9];
    float* out = (float*)d_out;
    float* wsf = (float*)d_ws;

    const int B = in_sizes[0] / 2;
    const int nblk = (B + 255) / 256;

    const size_t need = (WS_PK + (size_t)H * (H / 2)) * 4;

    if (ws_size >= need) {
        hipLaunchKernelGGL(setup_kernel, dim3(1), dim3(256), 0, stream,
                           W2, b1, b2, W3, b3, wsf);
        hipLaunchKernelGGL(sdnn_kernel, dim3(nblk), dim3(256), 0, stream,
                           X, Wf, W1, b1, W2, b2, W3, b3, Wim2, Wim3, wsf, out, B);
    } else {
        hipLaunchKernelGGL(g0_kernel, dim3(1), dim3(64), 0, stream,
                           W2, b1, b2, W3, b3, wsf);
        hipLaunchKernelGGL(sdnn_mono_kernel, dim3(nblk), dim3(256), 0, stream,
                           X, Wf, W1, b1, W2, b2, W3, b3, Wim2, Wim3, wsf, out, B);
    }
}